// Round 2
// baseline (50.572 us; speedup 1.0000x reference)
//
#include <hip/hip_runtime.h>
#include <hip/hip_bf16.h>

// RegionEmbeddingLayer: out[b,l,d] = max_{r<7}( word_emb[ids[b,l+r]][d] * ctx_emb[ids[b,l+3]][r*128+d] )
// B=32, S=2048, L=2042, D=128, REGION=7
// K=4 positions per thread: word rows for the union window [l0, l0+9] are
// loaded once into registers and feed up to 4 accumulators each.

#define RE_B 32
#define RE_S 2048
#define RE_RAD 3
#define RE_L (RE_S - 2 * RE_RAD)   // 2042
#define RE_D 128
#define RE_R 7
#define RE_DQ (RE_D / 4)           // 32 float4 per 128-dim row
#define KPOS 4
#define NCHUNK ((RE_L + KPOS - 1) / KPOS)   // 511

__global__ __launch_bounds__(256) void region_embed_kernel(
    const int* __restrict__ ids,        // [B, S]
    const float4* __restrict__ we,      // [V, 32]
    const float4* __restrict__ ce,      // [V, 7*32]
    float4* __restrict__ out)           // [B*L, 32]
{
    int idx = blockIdx.x * blockDim.x + threadIdx.x;
    int lane  = idx & (RE_DQ - 1);
    int chunk = idx >> 5;                // b * NCHUNK + c
    int b = chunk / NCHUNK;
    int c = chunk - b * NCHUNK;
    if (b >= RE_B) return;

    // clamp so the last chunk overlap-recomputes (idempotent writes)
    int l0 = c * KPOS;
    if (l0 > RE_L - KPOS) l0 = RE_L - KPOS;

    const int* row = ids + b * RE_S + l0;

    int wid[KPOS + 6];
#pragma unroll
    for (int i = 0; i < KPOS + 6; ++i) wid[i] = row[i];

    const float4* cb[KPOS];
#pragma unroll
    for (int k = 0; k < KPOS; ++k)
        cb[k] = ce + (size_t)wid[k + RE_RAD] * (RE_R * RE_DQ) + lane;

    float4 acc[KPOS];
#pragma unroll
    for (int k = 0; k < KPOS; ++k) {
        acc[k].x = -INFINITY; acc[k].y = -INFINITY;
        acc[k].z = -INFINITY; acc[k].w = -INFINITY;
    }

#pragma unroll
    for (int w = 0; w < KPOS + 6; ++w) {
        float4 ve = we[(size_t)wid[w] * RE_DQ + lane];
#pragma unroll
        for (int k = 0; k < KPOS; ++k) {
            int r = w - k;
            if (r >= 0 && r < RE_R) {
                float4 cv = cb[k][r * RE_DQ];
                acc[k].x = fmaxf(acc[k].x, ve.x * cv.x);
                acc[k].y = fmaxf(acc[k].y, ve.y * cv.y);
                acc[k].z = fmaxf(acc[k].z, ve.z * cv.z);
                acc[k].w = fmaxf(acc[k].w, ve.w * cv.w);
            }
        }
    }

    size_t obase = (size_t)(b * RE_L + l0) * RE_DQ + lane;
#pragma unroll
    for (int k = 0; k < KPOS; ++k)
        out[obase + (size_t)k * RE_DQ] = acc[k];
}

extern "C" void kernel_launch(void* const* d_in, const int* in_sizes, int n_in,
                              void* d_out, int out_size, void* d_ws, size_t ws_size,
                              hipStream_t stream) {
    const int*    ids = (const int*)d_in[0];
    const float4* we  = (const float4*)d_in[1];
    const float4* ce  = (const float4*)d_in[2];
    float4* out = (float4*)d_out;

    const int total = RE_B * NCHUNK * RE_DQ;   // 32*511*32 = 523,264 threads
    const int block = 256;
    const int grid = (total + block - 1) / block;   // 2044 blocks
    region_embed_kernel<<<grid, block, 0, stream>>>(ids, we, ce, out);
}

// Round 4
// 50.063 us; speedup vs baseline: 1.0102x; 1.0102x over previous
//
#include <hip/hip_runtime.h>
#include <hip/hip_bf16.h>

// RegionEmbeddingLayer: out[b,l,d] = max_{r<7}( word_emb[ids[b,l+r]][d] * ctx_emb[ids[b,l+3]][r*128+d] )
// B=32, S=2048, L=2042, D=128, REGION=7
// K=4 positions per thread; nontemporal output stores (out has zero reuse --
// keep it from write-allocating L2/L3 and evicting ctx gather rows).

#define RE_B 32
#define RE_S 2048
#define RE_RAD 3
#define RE_L (RE_S - 2 * RE_RAD)   // 2042
#define RE_D 128
#define RE_R 7
#define RE_DQ (RE_D / 4)           // 32 float4 per 128-dim row
#define KPOS 4
#define NCHUNK ((RE_L + KPOS - 1) / KPOS)   // 511

typedef float f32x4 __attribute__((ext_vector_type(4)));

__global__ __launch_bounds__(256) void region_embed_kernel(
    const int* __restrict__ ids,        // [B, S]
    const float4* __restrict__ we,      // [V, 32]
    const float4* __restrict__ ce,      // [V, 7*32]
    float4* __restrict__ out)           // [B*L, 32]
{
    int idx = blockIdx.x * blockDim.x + threadIdx.x;
    int lane  = idx & (RE_DQ - 1);
    int chunk = idx >> 5;                // b * NCHUNK + c
    int b = chunk / NCHUNK;
    int c = chunk - b * NCHUNK;
    if (b >= RE_B) return;

    // clamp so the last chunk overlap-recomputes (idempotent writes)
    int l0 = c * KPOS;
    if (l0 > RE_L - KPOS) l0 = RE_L - KPOS;

    const int* row = ids + b * RE_S + l0;

    int wid[KPOS + 6];
#pragma unroll
    for (int i = 0; i < KPOS + 6; ++i) wid[i] = row[i];

    const float4* cb[KPOS];
#pragma unroll
    for (int k = 0; k < KPOS; ++k)
        cb[k] = ce + (size_t)wid[k + RE_RAD] * (RE_R * RE_DQ) + lane;

    float4 acc[KPOS];
#pragma unroll
    for (int k = 0; k < KPOS; ++k) {
        acc[k].x = -INFINITY; acc[k].y = -INFINITY;
        acc[k].z = -INFINITY; acc[k].w = -INFINITY;
    }

#pragma unroll
    for (int w = 0; w < KPOS + 6; ++w) {
        float4 ve = we[(size_t)wid[w] * RE_DQ + lane];
#pragma unroll
        for (int k = 0; k < KPOS; ++k) {
            int r = w - k;
            if (r >= 0 && r < RE_R) {
                float4 cv = cb[k][r * RE_DQ];
                acc[k].x = fmaxf(acc[k].x, ve.x * cv.x);
                acc[k].y = fmaxf(acc[k].y, ve.y * cv.y);
                acc[k].z = fmaxf(acc[k].z, ve.z * cv.z);
                acc[k].w = fmaxf(acc[k].w, ve.w * cv.w);
            }
        }
    }

    f32x4* obase = (f32x4*)(out + (size_t)(b * RE_L + l0) * RE_DQ + lane);
#pragma unroll
    for (int k = 0; k < KPOS; ++k) {
        f32x4 v;
        v.x = acc[k].x; v.y = acc[k].y; v.z = acc[k].z; v.w = acc[k].w;
        __builtin_nontemporal_store(v, obase + (size_t)k * RE_DQ);
    }
}

extern "C" void kernel_launch(void* const* d_in, const int* in_sizes, int n_in,
                              void* d_out, int out_size, void* d_ws, size_t ws_size,
                              hipStream_t stream) {
    const int*    ids = (const int*)d_in[0];
    const float4* we  = (const float4*)d_in[1];
    const float4* ce  = (const float4*)d_in[2];
    float4* out = (float4*)d_out;

    const int total = RE_B * NCHUNK * RE_DQ;   // 32*511*32 = 523,264 threads
    const int block = 256;
    const int grid = (total + block - 1) / block;   // 2044 blocks
    region_embed_kernel<<<grid, block, 0, stream>>>(ids, we, ce, out);
}